// Round 2
// baseline (517.952 us; speedup 1.0000x reference)
//
#include <hip/hip_runtime.h>
#include <hip/hip_bf16.h>
#include <stdint.h>

#define B_  2
#define S_  4096
#define D_  768
#define H_  12
#define DH_ 64
#define BS_ (B_*S_)   // 8192

typedef __bf16 bf16x8 __attribute__((ext_vector_type(8)));
typedef short  svec8  __attribute__((ext_vector_type(8)));
typedef float  fvec4  __attribute__((ext_vector_type(4)));
typedef unsigned short ushort_t;

__device__ __forceinline__ ushort_t f2bf(float f){
    unsigned u = __builtin_bit_cast(unsigned, f);
    unsigned r = (u + 0x7fffu + ((u >> 16) & 1u)) >> 16;
    return (ushort_t)r;
}

__device__ __forceinline__ fvec4 mfma16(svec8 a, svec8 b, fvec4 c){
    return __builtin_amdgcn_mfma_f32_16x16x32_bf16(
        __builtin_bit_cast(bf16x8, a), __builtin_bit_cast(bf16x8, b), c, 0, 0, 0);
}

// ---------------- QKV projection (R8-passed, verbatim) ----------------
__global__ __launch_bounds__(256) void qkv_proj(
    const float* __restrict__ X,
    const float* __restrict__ Wq, const float* __restrict__ Wk, const float* __restrict__ Wv,
    ushort_t* __restrict__ Qb, ushort_t* __restrict__ Kb, ushort_t* __restrict__ Vg)
{
    const int m0 = blockIdx.x * 128;
    const int h  = blockIdx.y;
    const int wt = blockIdx.z;
    const float* W  = (wt == 0) ? Wq : (wt == 1) ? Wk : Wv;
    const float* Wh = W + (size_t)h * (D_ * DH_);
    const float oscale = (wt == 0) ? 0.18033688011112042f : 1.0f;  // 1/8 * log2(e) on Q

    __shared__ ushort_t smem[128 * 72 + 64 * 64];
    ushort_t* Xs  = smem;
    ushort_t* Wts = smem + 128 * 72;
    ushort_t* XsT = smem;              // 64 x 136 overlay, used after K-loop

    const int tid  = threadIdx.x;
    const int w    = tid >> 6;
    const int lane = tid & 63;
    const int quad = lane >> 4;
    const int l15  = lane & 15;

    fvec4 acc[2][4];
    #pragma unroll
    for (int i = 0; i < 2; i++)
        #pragma unroll
        for (int j = 0; j < 4; j++) acc[i][j] = (fvec4){0.f, 0.f, 0.f, 0.f};

    for (int k0 = 0; k0 < D_; k0 += 64) {
        #pragma unroll
        for (int i = 0; i < 4; i++) {
            int v = tid + 256 * i;
            int r = v >> 3, c = (v & 7) * 8;
            const float* src = X + (size_t)(m0 + r) * D_ + k0 + c;
            float4 d0 = *(const float4*)(src);
            float4 d1 = *(const float4*)(src + 4);
            svec8 pk;
            pk[0] = (short)f2bf(d0.x); pk[1] = (short)f2bf(d0.y);
            pk[2] = (short)f2bf(d0.z); pk[3] = (short)f2bf(d0.w);
            pk[4] = (short)f2bf(d1.x); pk[5] = (short)f2bf(d1.y);
            pk[6] = (short)f2bf(d1.z); pk[7] = (short)f2bf(d1.w);
            *(svec8*)(Xs + r * 72 + c) = pk;
        }
        #pragma unroll
        for (int i = 0; i < 4; i++) {
            int v = tid + 256 * i;
            int k = v >> 4, t = v & 15;
            float4 d = *(const float4*)(Wh + (size_t)(k0 + k) * DH_ + t * 4);
            #pragma unroll
            for (int j = 0; j < 4; j++) {
                int n = t * 4 + j;
                int addr = n * 64 + ((((k >> 3) ^ (t & 7))) << 3) + (k & 7);
                Wts[addr] = f2bf(j == 0 ? d.x : j == 1 ? d.y : j == 2 ? d.z : d.w);
            }
        }
        __syncthreads();

        #pragma unroll
        for (int ks = 0; ks < 2; ks++) {
            svec8 a0 = *(const svec8*)(Xs + (32 * w + l15) * 72 + ks * 32 + quad * 8);
            svec8 a1 = *(const svec8*)(Xs + (32 * w + 16 + l15) * 72 + ks * 32 + quad * 8);
            #pragma unroll
            for (int ns = 0; ns < 4; ns++) {
                int n = ns * 16 + l15;
                int swz = (ks * 4 + quad) ^ ((n >> 2) & 7);
                svec8 b = *(const svec8*)(Wts + n * 64 + swz * 8);
                acc[0][ns] = mfma16(a0, b, acc[0][ns]);
                acc[1][ns] = mfma16(a1, b, acc[1][ns]);
            }
        }
        __syncthreads();
    }

    if (wt != 2) {
        ushort_t* Out = (wt == 0) ? Qb : Kb;
        #pragma unroll
        for (int ms = 0; ms < 2; ms++)
            #pragma unroll
            for (int ns = 0; ns < 4; ns++)
                #pragma unroll
                for (int r = 0; r < 4; r++) {
                    int row = m0 + 32 * w + ms * 16 + quad * 4 + r;
                    int col = h * DH_ + ns * 16 + l15;
                    Out[(size_t)row * D_ + col] = f2bf(acc[ms][ns][r] * oscale);
                }
    } else {
        #pragma unroll
        for (int ms = 0; ms < 2; ms++)
            #pragma unroll
            for (int ns = 0; ns < 4; ns++)
                #pragma unroll
                for (int r = 0; r < 4; r++) {
                    int sl = 32 * w + ms * 16 + quad * 4 + r;
                    int e  = ns * 16 + l15;
                    XsT[e * 136 + sl] = f2bf(acc[ms][ns][r]);
                }
        __syncthreads();
        #pragma unroll
        for (int i = 0; i < 4; i++) {
            int v = tid + 256 * i;
            int e = v >> 4, s0 = (v & 15) * 8;
            svec8 d = *(const svec8*)(XsT + e * 136 + s0);
            *(svec8*)(Vg + (size_t)(h * DH_ + e) * BS_ + m0 + s0) = d;
        }
    }
}

// ---------------- causal flash attention (R10: in-register P, 8 blk/CU) -------------
// Flat de-aliased grid (R9). NEW this round:
//
// Swapped QK^T + permuted K rows -> P never touches LDS. We compute S^T = K_perm Q^T
// (A = K tile, B = Q), so output col = l15 = q: each lane holds one full q-row.
// K rows are staged at LDS row pinv(k) so that LDS row m holds key
//   pi(m) = n0*32 + quad*8 + n1*4 + r   (m = n*16 + quad*4 + r, n = n1:n0)
// which makes the lane's 16 score registers EXACTLY the PV A-fragment keys
// {ks*32 + quad*8 + j}:  ap[ks][j] = p[(j>>2)*2 + ks][j&3]  -- lane-local, zero
// shuffles, zero LDS. Removes per tile: 16 ds_write_b16 (the 4-way-conflicted P
// stores), 2 ds_read_b128, and the serializing lgkmcnt(0) drain. Row-max reduce
// shrinks 6 shuffles -> 2 (quads xor16/xor32); max/denominator are now per-row.
// Cost: 4 bpermutes to fetch alpha for acc rows (quad*4+r) + 4 in the epilogue.
// Ps LDS freed: 27648 -> 18432 B => 8 blocks/CU (32 waves, full occupancy);
// __launch_bounds__(256,8) pins VGPR <= 64 so the register limit matches.
__global__ __launch_bounds__(256, 8) void attn(
    const ushort_t* __restrict__ Qb, const ushort_t* __restrict__ Kb,
    const ushort_t* __restrict__ Vg, float* __restrict__ Out)
{
    const int fid = blockIdx.x;                        // 0..1535 flat
    const int qt  = (S_ / 64 - 1) - fid / (H_ * B_);   // long tiles first, de-aliased
    const int r24 = fid % (H_ * B_);
    const int h   = r24 % H_;
    const int b   = r24 / H_;
    const int q0 = qt * 64;

    const int tid  = threadIdx.x;
    const int w    = tid >> 6;
    const int lane = tid & 63;
    const int quad = lane >> 4;
    const int l15  = lane & 15;

    __shared__ ushort_t Ks[64 * 72];       // K tile, ROW-PERMUTED: LDS row m = key pi(m)
    __shared__ ushort_t Vt[64 * 72];       // V^T tile [e][key]

    const size_t hb = (size_t)b * S_ * D_ + (size_t)h * DH_;
    const ushort_t* Vh = Vg + (size_t)h * DH_ * BS_ + (size_t)b * S_;

    const int sr = tid >> 3;          // staging row 0..31 (+32)
    const int sc = (tid & 7) * 8;
    // pinv(k): LDS row where key k lives.  m4=k5, m3=k4, m2=k3, m5=k2, m1m0=k1k0
    const int pr0 = (((sr      >> 2) & 1) << 5) | (((sr      >> 5) & 1) << 4) |
                    (((sr      >> 4) & 1) << 3) | (((sr      >> 3) & 1) << 2) | (sr & 3);
    const int sr1 = sr + 32;
    const int pr1 = (((sr1 >> 2) & 1) << 5) | (((sr1 >> 5) & 1) << 4) |
                    (((sr1 >> 4) & 1) << 3) | (((sr1 >> 3) & 1) << 2) | (sr1 & 3);

    // Q fragments (pre-scaled to log2 domain in qkv_proj); B-operand now, same layout
    svec8 aq[2];
    {
        const ushort_t* qrow = Qb + hb + (size_t)(q0 + 16 * w + l15) * D_;
        aq[0] = *(const svec8*)(qrow + quad * 8);
        aq[1] = *(const svec8*)(qrow + 32 + quad * 8);
    }

    float m_i = -INFINITY;
    float ls  = 0.f;                  // per-lane partial denominator (row q = l15)
    fvec4 acc[4];
    #pragma unroll
    for (int n = 0; n < 4; n++) acc[n] = (fvec4){0.f, 0.f, 0.f, 0.f};

    // prologue: stage tile 0
    svec8 kd[2], vd[2];
    #pragma unroll
    for (int i = 0; i < 2; i++) {
        int r = sr + 32 * i;
        kd[i] = *(const svec8*)(Kb + hb + (size_t)r * D_ + sc);
        vd[i] = *(const svec8*)(Vh + (size_t)r * BS_ + sc);
    }
    *(svec8*)(Ks + pr0 * 72 + sc) = kd[0];
    *(svec8*)(Ks + pr1 * 72 + sc) = kd[1];
    *(svec8*)(Vt + sr  * 72 + sc) = vd[0];
    *(svec8*)(Vt + sr1 * 72 + sc) = vd[1];

    for (int kt = 0; kt <= qt; ++kt) {
        __syncthreads();   // staged tile kt visible to all waves

        // prefetch next tile into registers (in flight across the compute phase)
        if (kt < qt) {
            #pragma unroll
            for (int i = 0; i < 2; i++) {
                int r = sr + 32 * i;
                kd[i] = *(const svec8*)(Kb + hb + (size_t)((kt + 1) * 64 + r) * D_ + sc);
                vd[i] = *(const svec8*)(Vh + (size_t)r * BS_ + (kt + 1) * 64 + sc);
            }
        }

        // S^T = K_perm Q^T  (log2 domain via pre-scaled Q); lane holds row q = l15
        fvec4 st[4];
        #pragma unroll
        for (int n = 0; n < 4; n++) st[n] = (fvec4){0.f, 0.f, 0.f, 0.f};
        #pragma unroll
        for (int ks = 0; ks < 2; ks++)
            #pragma unroll
            for (int n = 0; n < 4; n++) {
                svec8 ka = *(const svec8*)(Ks + (n * 16 + l15) * 72 + ks * 32 + quad * 8);
                st[n] = mfma16(ka, aq[ks], st[n]);
            }

        // causal mask on the diagonal tile: key pi(m) vs q row
        if (kt == qt) {
            #pragma unroll
            for (int n = 0; n < 4; n++)
                #pragma unroll
                for (int r = 0; r < 4; r++) {
                    int key = (n & 1) * 32 + quad * 8 + (n >> 1) * 4 + r;
                    int row = 16 * w + l15;
                    if (key > row) st[n][r] = -INFINITY;
                }
        }

        // per-row max: in-lane tree over 16, then 2-step butterfly across quads
        float mx = fmaxf(fmaxf(fmaxf(st[0][0], st[0][1]), fmaxf(st[0][2], st[0][3])),
                         fmaxf(fmaxf(st[1][0], st[1][1]), fmaxf(st[1][2], st[1][3])));
        float mx2 = fmaxf(fmaxf(fmaxf(st[2][0], st[2][1]), fmaxf(st[2][2], st[2][3])),
                          fmaxf(fmaxf(st[3][0], st[3][1]), fmaxf(st[3][2], st[3][3])));
        mx = fmaxf(mx, mx2);
        mx = fmaxf(mx, __shfl_xor(mx, 16));
        mx = fmaxf(mx, __shfl_xor(mx, 32));
        float mn = fmaxf(m_i, mx);
        float alpha = exp2f(m_i - mn);
        m_i = mn;
        ls *= alpha;

        // p = exp2(st - m); pack directly into PV A-fragments (truncation to bf16:
        // p in [0,1] so rel err <= 2^-8)
        svec8 ap0, ap1;
        #pragma unroll
        for (int n = 0; n < 4; n++)
            #pragma unroll
            for (int r = 0; r < 4; r++) {
                float p = exp2f(st[n][r] - mn);
                ls += p;
                ushort_t pb = (ushort_t)(__builtin_bit_cast(unsigned, p) >> 16);
                if (n & 1) ap1[(n >> 1) * 4 + r] = (short)pb;
                else       ap0[(n >> 1) * 4 + r] = (short)pb;
            }

        // fetch alpha for the acc rows (quad*4+r) from the lane owning that row
        float ar[4];
        #pragma unroll
        for (int r = 0; r < 4; r++)
            ar[r] = __shfl(alpha, quad * 16 + quad * 4 + r);
        #pragma unroll
        for (int n = 0; n < 4; n++)
            #pragma unroll
            for (int r = 0; r < 4; r++) acc[n][r] *= ar[r];

        // O += P V   (A = in-register P fragment, B = V^T from LDS)
        #pragma unroll
        for (int ks = 0; ks < 2; ks++) {
            svec8 ap = ks ? ap1 : ap0;
            #pragma unroll
            for (int n = 0; n < 4; n++) {
                svec8 bv = *(const svec8*)(Vt + (n * 16 + l15) * 72 + ks * 32 + quad * 8);
                acc[n] = mfma16(ap, bv, acc[n]);
            }
        }

        __syncthreads();   // all waves done reading tile kt

        if (kt < qt) {
            *(svec8*)(Ks + pr0 * 72 + sc) = kd[0];
            *(svec8*)(Ks + pr1 * 72 + sc) = kd[1];
            *(svec8*)(Vt + sr  * 72 + sc) = vd[0];
            *(svec8*)(Vt + sr1 * 72 + sc) = vd[1];
        }
    }

    // epilogue: full denominator for row l15 (2 shuffles), then fetch per-acc-row
    float lsum = ls;
    lsum += __shfl_xor(lsum, 16);
    lsum += __shfl_xor(lsum, 32);
    float li[4];
    #pragma unroll
    for (int r = 0; r < 4; r++)
        li[r] = __shfl(lsum, quad * 16 + quad * 4 + r);
    #pragma unroll
    for (int n = 0; n < 4; n++)
        #pragma unroll
        for (int r = 0; r < 4; r++) {
            int row = q0 + 16 * w + quad * 4 + r;
            int col = h * DH_ + n * 16 + l15;
            Out[((size_t)b * S_ + row) * D_ + col] = acc[n][r] / li[r];
        }
}

extern "C" void kernel_launch(void* const* d_in, const int* in_sizes, int n_in,
                              void* d_out, int out_size, void* d_ws, size_t ws_size,
                              hipStream_t stream)
{
    const float* X  = (const float*)d_in[0];
    const float* Wq = (const float*)d_in[1];
    const float* Wk = (const float*)d_in[2];
    const float* Wv = (const float*)d_in[3];

    ushort_t* Qb = (ushort_t*)d_ws;                      // 8192*768 bf16 (pre-scaled)
    ushort_t* Kb = Qb + (size_t)BS_ * D_;                // 8192*768 bf16
    ushort_t* Vg = Kb + (size_t)BS_ * D_;                // [768][8192] bf16 transposed
    float* Out = (float*)d_out;

    qkv_proj<<<dim3(64, H_, 3), dim3(256), 0, stream>>>(X, Wq, Wk, Wv, Qb, Kb, Vg);
    attn<<<dim3((S_ / 64) * H_ * B_), dim3(256), 0, stream>>>(Qb, Kb, Vg, Out);
}

// Round 3
// 250.286 us; speedup vs baseline: 2.0694x; 2.0694x over previous
//
#include <hip/hip_runtime.h>
#include <hip/hip_bf16.h>
#include <stdint.h>

#define B_  2
#define S_  4096
#define D_  768
#define H_  12
#define DH_ 64
#define BS_ (B_*S_)   // 8192

typedef __bf16 bf16x8 __attribute__((ext_vector_type(8)));
typedef short  svec8  __attribute__((ext_vector_type(8)));
typedef float  fvec4  __attribute__((ext_vector_type(4)));
typedef unsigned short ushort_t;

__device__ __forceinline__ ushort_t f2bf(float f){
    unsigned u = __builtin_bit_cast(unsigned, f);
    unsigned r = (u + 0x7fffu + ((u >> 16) & 1u)) >> 16;
    return (ushort_t)r;
}

__device__ __forceinline__ fvec4 mfma16(svec8 a, svec8 b, fvec4 c){
    return __builtin_amdgcn_mfma_f32_16x16x32_bf16(
        __builtin_bit_cast(bf16x8, a), __builtin_bit_cast(bf16x8, b), c, 0, 0, 0);
}

// ---------------- QKV projection (R8-passed, verbatim) ----------------
__global__ __launch_bounds__(256) void qkv_proj(
    const float* __restrict__ X,
    const float* __restrict__ Wq, const float* __restrict__ Wk, const float* __restrict__ Wv,
    ushort_t* __restrict__ Qb, ushort_t* __restrict__ Kb, ushort_t* __restrict__ Vg)
{
    const int m0 = blockIdx.x * 128;
    const int h  = blockIdx.y;
    const int wt = blockIdx.z;
    const float* W  = (wt == 0) ? Wq : (wt == 1) ? Wk : Wv;
    const float* Wh = W + (size_t)h * (D_ * DH_);
    const float oscale = (wt == 0) ? 0.18033688011112042f : 1.0f;  // 1/8 * log2(e) on Q

    __shared__ ushort_t smem[128 * 72 + 64 * 64];
    ushort_t* Xs  = smem;
    ushort_t* Wts = smem + 128 * 72;
    ushort_t* XsT = smem;              // 64 x 136 overlay, used after K-loop

    const int tid  = threadIdx.x;
    const int w    = tid >> 6;
    const int lane = tid & 63;
    const int quad = lane >> 4;
    const int l15  = lane & 15;

    fvec4 acc[2][4];
    #pragma unroll
    for (int i = 0; i < 2; i++)
        #pragma unroll
        for (int j = 0; j < 4; j++) acc[i][j] = (fvec4){0.f, 0.f, 0.f, 0.f};

    for (int k0 = 0; k0 < D_; k0 += 64) {
        #pragma unroll
        for (int i = 0; i < 4; i++) {
            int v = tid + 256 * i;
            int r = v >> 3, c = (v & 7) * 8;
            const float* src = X + (size_t)(m0 + r) * D_ + k0 + c;
            float4 d0 = *(const float4*)(src);
            float4 d1 = *(const float4*)(src + 4);
            svec8 pk;
            pk[0] = (short)f2bf(d0.x); pk[1] = (short)f2bf(d0.y);
            pk[2] = (short)f2bf(d0.z); pk[3] = (short)f2bf(d0.w);
            pk[4] = (short)f2bf(d1.x); pk[5] = (short)f2bf(d1.y);
            pk[6] = (short)f2bf(d1.z); pk[7] = (short)f2bf(d1.w);
            *(svec8*)(Xs + r * 72 + c) = pk;
        }
        #pragma unroll
        for (int i = 0; i < 4; i++) {
            int v = tid + 256 * i;
            int k = v >> 4, t = v & 15;
            float4 d = *(const float4*)(Wh + (size_t)(k0 + k) * DH_ + t * 4);
            #pragma unroll
            for (int j = 0; j < 4; j++) {
                int n = t * 4 + j;
                int addr = n * 64 + ((((k >> 3) ^ (t & 7))) << 3) + (k & 7);
                Wts[addr] = f2bf(j == 0 ? d.x : j == 1 ? d.y : j == 2 ? d.z : d.w);
            }
        }
        __syncthreads();

        #pragma unroll
        for (int ks = 0; ks < 2; ks++) {
            svec8 a0 = *(const svec8*)(Xs + (32 * w + l15) * 72 + ks * 32 + quad * 8);
            svec8 a1 = *(const svec8*)(Xs + (32 * w + 16 + l15) * 72 + ks * 32 + quad * 8);
            #pragma unroll
            for (int ns = 0; ns < 4; ns++) {
                int n = ns * 16 + l15;
                int swz = (ks * 4 + quad) ^ ((n >> 2) & 7);
                svec8 b = *(const svec8*)(Wts + n * 64 + swz * 8);
                acc[0][ns] = mfma16(a0, b, acc[0][ns]);
                acc[1][ns] = mfma16(a1, b, acc[1][ns]);
            }
        }
        __syncthreads();
    }

    if (wt != 2) {
        ushort_t* Out = (wt == 0) ? Qb : Kb;
        #pragma unroll
        for (int ms = 0; ms < 2; ms++)
            #pragma unroll
            for (int ns = 0; ns < 4; ns++)
                #pragma unroll
                for (int r = 0; r < 4; r++) {
                    int row = m0 + 32 * w + ms * 16 + quad * 4 + r;
                    int col = h * DH_ + ns * 16 + l15;
                    Out[(size_t)row * D_ + col] = f2bf(acc[ms][ns][r] * oscale);
                }
    } else {
        #pragma unroll
        for (int ms = 0; ms < 2; ms++)
            #pragma unroll
            for (int ns = 0; ns < 4; ns++)
                #pragma unroll
                for (int r = 0; r < 4; r++) {
                    int sl = 32 * w + ms * 16 + quad * 4 + r;
                    int e  = ns * 16 + l15;
                    XsT[e * 136 + sl] = f2bf(acc[ms][ns][r]);
                }
        __syncthreads();
        #pragma unroll
        for (int i = 0; i < 4; i++) {
            int v = tid + 256 * i;
            int e = v >> 4, s0 = (v & 15) * 8;
            svec8 d = *(const svec8*)(XsT + e * 136 + s0);
            *(svec8*)(Vg + (size_t)(h * DH_ + e) * BS_ + m0 + s0) = d;
        }
    }
}

// ---------------- causal flash attention (R11: in-register P, spill-free) -----------
// Flat de-aliased grid (R9) + swapped QK^T / in-register P (R10).
//
// R11 fix: R10's __launch_bounds__(256,8) capped VGPR at 64 but the in-register-P
// structure needs ~80-90 (acc 16 + aq 8 + kd/vd 16 prefetch + st/ap transients).
// The compiler spilled to scratch: VGPR_Count=32, FETCH 23->462 MB, WRITE 25->777 MB
// (1.24 GB/dispatch of scratch round-trip), MfmaUtil 5.5%, dur 389 us. Relax to
// (256,5): cap ~96 VGPR, zero spills, 5 blocks/CU (20 waves) -- same residency as
// R9 but each tile lacks the P LDS round-trip, the lgkmcnt(0) drain, and 8 of 10
// reduction shuffles.
//
// Swapped QK^T + permuted K rows -> P never touches LDS. S^T = K_perm Q^T
// (A = K tile, B = Q): output col = l15 = q, so each lane holds one full q-row.
// K rows staged at LDS row pinv(k); LDS row m holds key
//   pi(m) = n0*32 + quad*8 + n1*4 + r   (m = n*16 + quad*4 + r, n = n1:n0)
// making the lane's 16 score registers EXACTLY the PV A-fragment keys
// {ks*32 + quad*8 + j}:  ap[ks][j] = p[(j>>2)*2 + ks][j&3] -- lane-local, zero
// shuffles, zero LDS. Row max/denominator reduce = 2 shuffles (xor16/xor32).
__global__ __launch_bounds__(256, 5) void attn(
    const ushort_t* __restrict__ Qb, const ushort_t* __restrict__ Kb,
    const ushort_t* __restrict__ Vg, float* __restrict__ Out)
{
    const int fid = blockIdx.x;                        // 0..1535 flat
    const int qt  = (S_ / 64 - 1) - fid / (H_ * B_);   // long tiles first, de-aliased
    const int r24 = fid % (H_ * B_);
    const int h   = r24 % H_;
    const int b   = r24 / H_;
    const int q0 = qt * 64;

    const int tid  = threadIdx.x;
    const int w    = tid >> 6;
    const int lane = tid & 63;
    const int quad = lane >> 4;
    const int l15  = lane & 15;

    __shared__ ushort_t Ks[64 * 72];       // K tile, ROW-PERMUTED: LDS row m = key pi(m)
    __shared__ ushort_t Vt[64 * 72];       // V^T tile [e][key]

    const size_t hb = (size_t)b * S_ * D_ + (size_t)h * DH_;
    const ushort_t* Vh = Vg + (size_t)h * DH_ * BS_ + (size_t)b * S_;

    const int sr = tid >> 3;          // staging row 0..31 (+32)
    const int sc = (tid & 7) * 8;
    // pinv(k): LDS row where key k lives.  m4=k5, m3=k4, m2=k3, m5=k2, m1m0=k1k0
    const int pr0 = (((sr      >> 2) & 1) << 5) | (((sr      >> 5) & 1) << 4) |
                    (((sr      >> 4) & 1) << 3) | (((sr      >> 3) & 1) << 2) | (sr & 3);
    const int sr1 = sr + 32;
    const int pr1 = (((sr1 >> 2) & 1) << 5) | (((sr1 >> 5) & 1) << 4) |
                    (((sr1 >> 4) & 1) << 3) | (((sr1 >> 3) & 1) << 2) | (sr1 & 3);

    // Q fragments (pre-scaled to log2 domain in qkv_proj); B-operand now, same layout
    svec8 aq[2];
    {
        const ushort_t* qrow = Qb + hb + (size_t)(q0 + 16 * w + l15) * D_;
        aq[0] = *(const svec8*)(qrow + quad * 8);
        aq[1] = *(const svec8*)(qrow + 32 + quad * 8);
    }

    float m_i = -INFINITY;
    float ls  = 0.f;                  // per-lane partial denominator (row q = l15)
    fvec4 acc[4];
    #pragma unroll
    for (int n = 0; n < 4; n++) acc[n] = (fvec4){0.f, 0.f, 0.f, 0.f};

    // prologue: stage tile 0
    svec8 kd[2], vd[2];
    #pragma unroll
    for (int i = 0; i < 2; i++) {
        int r = sr + 32 * i;
        kd[i] = *(const svec8*)(Kb + hb + (size_t)r * D_ + sc);
        vd[i] = *(const svec8*)(Vh + (size_t)r * BS_ + sc);
    }
    *(svec8*)(Ks + pr0 * 72 + sc) = kd[0];
    *(svec8*)(Ks + pr1 * 72 + sc) = kd[1];
    *(svec8*)(Vt + sr  * 72 + sc) = vd[0];
    *(svec8*)(Vt + sr1 * 72 + sc) = vd[1];

    for (int kt = 0; kt <= qt; ++kt) {
        __syncthreads();   // staged tile kt visible to all waves

        // prefetch next tile into registers (in flight across the compute phase)
        if (kt < qt) {
            #pragma unroll
            for (int i = 0; i < 2; i++) {
                int r = sr + 32 * i;
                kd[i] = *(const svec8*)(Kb + hb + (size_t)((kt + 1) * 64 + r) * D_ + sc);
                vd[i] = *(const svec8*)(Vh + (size_t)r * BS_ + (kt + 1) * 64 + sc);
            }
        }

        // S^T = K_perm Q^T  (log2 domain via pre-scaled Q); lane holds row q = l15
        fvec4 st[4];
        #pragma unroll
        for (int n = 0; n < 4; n++) st[n] = (fvec4){0.f, 0.f, 0.f, 0.f};
        #pragma unroll
        for (int ks = 0; ks < 2; ks++)
            #pragma unroll
            for (int n = 0; n < 4; n++) {
                svec8 ka = *(const svec8*)(Ks + (n * 16 + l15) * 72 + ks * 32 + quad * 8);
                st[n] = mfma16(ka, aq[ks], st[n]);
            }

        // causal mask on the diagonal tile: key pi(m) vs q row
        if (kt == qt) {
            #pragma unroll
            for (int n = 0; n < 4; n++)
                #pragma unroll
                for (int r = 0; r < 4; r++) {
                    int key = (n & 1) * 32 + quad * 8 + (n >> 1) * 4 + r;
                    int row = 16 * w + l15;
                    if (key > row) st[n][r] = -INFINITY;
                }
        }

        // per-row max: in-lane tree over 16, then 2-step butterfly across quads
        float mx = fmaxf(fmaxf(fmaxf(st[0][0], st[0][1]), fmaxf(st[0][2], st[0][3])),
                         fmaxf(fmaxf(st[1][0], st[1][1]), fmaxf(st[1][2], st[1][3])));
        float mx2 = fmaxf(fmaxf(fmaxf(st[2][0], st[2][1]), fmaxf(st[2][2], st[2][3])),
                          fmaxf(fmaxf(st[3][0], st[3][1]), fmaxf(st[3][2], st[3][3])));
        mx = fmaxf(mx, mx2);
        mx = fmaxf(mx, __shfl_xor(mx, 16));
        mx = fmaxf(mx, __shfl_xor(mx, 32));
        float mn = fmaxf(m_i, mx);
        float alpha = exp2f(m_i - mn);
        m_i = mn;
        ls *= alpha;

        // p = exp2(st - m); pack directly into PV A-fragments (truncation to bf16:
        // p in [0,1] so rel err <= 2^-8)
        svec8 ap0, ap1;
        #pragma unroll
        for (int n = 0; n < 4; n++)
            #pragma unroll
            for (int r = 0; r < 4; r++) {
                float p = exp2f(st[n][r] - mn);
                ls += p;
                ushort_t pb = (ushort_t)(__builtin_bit_cast(unsigned, p) >> 16);
                if (n & 1) ap1[(n >> 1) * 4 + r] = (short)pb;
                else       ap0[(n >> 1) * 4 + r] = (short)pb;
            }

        // fetch alpha for the acc rows (quad*4+r) from the lane owning that row
        float ar[4];
        #pragma unroll
        for (int r = 0; r < 4; r++)
            ar[r] = __shfl(alpha, quad * 16 + quad * 4 + r);
        #pragma unroll
        for (int n = 0; n < 4; n++)
            #pragma unroll
            for (int r = 0; r < 4; r++) acc[n][r] *= ar[r];

        // O += P V   (A = in-register P fragment, B = V^T from LDS)
        #pragma unroll
        for (int ks = 0; ks < 2; ks++) {
            svec8 ap = ks ? ap1 : ap0;
            #pragma unroll
            for (int n = 0; n < 4; n++) {
                svec8 bv = *(const svec8*)(Vt + (n * 16 + l15) * 72 + ks * 32 + quad * 8);
                acc[n] = mfma16(ap, bv, acc[n]);
            }
        }

        __syncthreads();   // all waves done reading tile kt

        if (kt < qt) {
            *(svec8*)(Ks + pr0 * 72 + sc) = kd[0];
            *(svec8*)(Ks + pr1 * 72 + sc) = kd[1];
            *(svec8*)(Vt + sr  * 72 + sc) = vd[0];
            *(svec8*)(Vt + sr1 * 72 + sc) = vd[1];
        }
    }

    // epilogue: full denominator for row l15 (2 shuffles), then fetch per-acc-row
    float lsum = ls;
    lsum += __shfl_xor(lsum, 16);
    lsum += __shfl_xor(lsum, 32);
    float li[4];
    #pragma unroll
    for (int r = 0; r < 4; r++)
        li[r] = __shfl(lsum, quad * 16 + quad * 4 + r);
    #pragma unroll
    for (int n = 0; n < 4; n++)
        #pragma unroll
        for (int r = 0; r < 4; r++) {
            int row = q0 + 16 * w + quad * 4 + r;
            int col = h * DH_ + n * 16 + l15;
            Out[((size_t)b * S_ + row) * D_ + col] = acc[n][r] / li[r];
        }
}

extern "C" void kernel_launch(void* const* d_in, const int* in_sizes, int n_in,
                              void* d_out, int out_size, void* d_ws, size_t ws_size,
                              hipStream_t stream)
{
    const float* X  = (const float*)d_in[0];
    const float* Wq = (const float*)d_in[1];
    const float* Wk = (const float*)d_in[2];
    const float* Wv = (const float*)d_in[3];

    ushort_t* Qb = (ushort_t*)d_ws;                      // 8192*768 bf16 (pre-scaled)
    ushort_t* Kb = Qb + (size_t)BS_ * D_;                // 8192*768 bf16
    ushort_t* Vg = Kb + (size_t)BS_ * D_;                // [768][8192] bf16 transposed
    float* Out = (float*)d_out;

    qkv_proj<<<dim3(64, H_, 3), dim3(256), 0, stream>>>(X, Wq, Wk, Wv, Qb, Kb, Vg);
    attn<<<dim3((S_ / 64) * H_ * B_), dim3(256), 0, stream>>>(Qb, Kb, Vg, Out);
}